// Round 1
// baseline (7862.440 us; speedup 1.0000x reference)
//
#include <hip/hip_runtime.h>
#include <hip/hip_fp16.h>

static constexpr int BLK = 256;

// --- detect whether edgeij_pair is int64 (expected) or int32 (JAX x64 off) ---
__global__ void detect_kernel(const unsigned long long* __restrict__ rc,
                              int* __restrict__ flag) {
    if (blockIdx.x == 0 && threadIdx.x == 0) {
        int is64 = 1;
        for (int i = 0; i < 8; ++i)
            if (rc[i] >= (1ull << 20)) is64 = 0;   // int32 pair packed in 8B -> huge
        *flag = is64;
    }
}

// --- pack (col:20 | row:20 | A_ij:f16 << 48) into one uint64 per edge ---
__global__ void pack_kernel(const void* __restrict__ rcv,
                            const float2* __restrict__ eattr,
                            const int* __restrict__ flag,
                            unsigned long long* __restrict__ pk, int ne) {
    int e = blockIdx.x * BLK + threadIdx.x;
    if (e >= ne) return;
    unsigned long long row, col;
    if (*flag) {
        const unsigned long long* rc = (const unsigned long long*)rcv;
        row = rc[e];
        col = rc[(size_t)ne + e];
    } else {
        const unsigned int* rc = (const unsigned int*)rcv;
        row = rc[e];
        col = rc[(size_t)ne + e];
    }
    float a = eattr[e].x;                       // A_ij (interleaved with zeros)
    unsigned short h = __half_as_ushort(__float2half(a));
    pk[e] = col | (row << 20) | ((unsigned long long)h << 48);
}

// --- vertex preprocessing: wbA = w*b/A, wA = w/A, x0, cbar=0 ---
__global__ void vprep_kernel(const float* __restrict__ vattr,
                             const float* __restrict__ g,
                             float2* __restrict__ vp,
                             float* __restrict__ x0,
                             float* __restrict__ cbar, int nv) {
    int i = blockIdx.x * BLK + threadIdx.x;
    if (i >= nv) return;
    float A = vattr[3 * i + 0];
    float b = vattr[3 * i + 1];
    float x = vattr[3 * i + 2];
    float w = g[0];
    vp[i]   = make_float2(w * b / A, w / A);
    x0[i]   = x;
    cbar[i] = 0.0f;
}

// --- per-iteration edge pass: cbar[row] += A_ij * x[col] ---
__global__ void edge_kernel(const unsigned long long* __restrict__ pk,
                            const float* __restrict__ x,
                            float* __restrict__ cbar, int ne) {
    int e = blockIdx.x * BLK + threadIdx.x;
    if (e >= ne) return;
    unsigned long long u = pk[e];
    int col = (int)(u & 0xFFFFFull);
    int row = (int)((u >> 20) & 0xFFFFFull);
    float a = __half2float(__ushort_as_half((unsigned short)(u >> 48)));
    atomicAdd(&cbar[row], a * x[col]);
}

// --- per-iteration vertex pass: x += wbA - wA*cbar ; cbar = 0 ---
__global__ void vertex_kernel(const float2* __restrict__ vp,
                              const float* __restrict__ xin,
                              float* __restrict__ cbar,
                              float* __restrict__ xout, int nv) {
    int i = blockIdx.x * BLK + threadIdx.x;
    if (i >= nv) return;
    float2 q = vp[i];
    xout[i] = xin[i] + q.x - q.y * cbar[i];
    cbar[i] = 0.0f;
}

extern "C" void kernel_launch(void* const* d_in, const int* in_sizes, int n_in,
                              void* d_out, int out_size, void* d_ws, size_t ws_size,
                              hipStream_t stream) {
    const float* vattr = (const float*)d_in[1];
    const void*  eij   = (const void*)d_in[2];
    const float* eattr = (const float*)d_in[3];
    const float* g     = (const float*)d_in[4];
    const int nv = in_sizes[1] / 3;   // 1,000,000
    const int ne = in_sizes[3] / 2;   // 16,000,000
    const int n_iters = 10;           // graph capture requires static topology

    // workspace layout
    char* ws = (char*)d_ws;
    size_t off = 0;
    auto alloc = [&](size_t bytes) -> void* {
        void* p = ws + off;
        off = (off + bytes + 255) & ~(size_t)255;
        return p;
    };
    unsigned long long* pk = (unsigned long long*)alloc((size_t)ne * 8);
    float2* vp   = (float2*)alloc((size_t)nv * 8);
    float*  xa   = (float*) alloc((size_t)nv * 4);
    float*  xb   = (float*) alloc((size_t)nv * 4);
    float*  cbar = (float*) alloc((size_t)nv * 4);
    int*    flag = (int*)   alloc(256);

    const int eblocks = (ne + BLK - 1) / BLK;
    const int vblocks = (nv + BLK - 1) / BLK;

    detect_kernel<<<1, 64, 0, stream>>>((const unsigned long long*)eij, flag);
    pack_kernel<<<eblocks, BLK, 0, stream>>>(eij, (const float2*)eattr, flag, pk, ne);
    vprep_kernel<<<vblocks, BLK, 0, stream>>>(vattr, g, vp, xa, cbar, nv);

    float* xin  = xa;
    float* xout = xb;
    for (int it = 0; it < n_iters; ++it) {
        edge_kernel<<<eblocks, BLK, 0, stream>>>(pk, xin, cbar, ne);
        float* dst = (it == n_iters - 1) ? (float*)d_out : xout;
        vertex_kernel<<<vblocks, BLK, 0, stream>>>(vp, xin, cbar, dst, nv);
        float* t = xin; xin = dst; xout = t;
    }
}

// Round 2
// 5384.919 us; speedup vs baseline: 1.4601x; 1.4601x over previous
//
#include <hip/hip_runtime.h>

static constexpr int BLK = 256;

// --- detect whether edgeij_pair is int64 (expected) or int32 (JAX x64 off) ---
__global__ void detect_kernel(const unsigned long long* __restrict__ rc,
                              int* __restrict__ flag) {
    if (blockIdx.x == 0 && threadIdx.x == 0) {
        int is64 = 1;
        for (int i = 0; i < 8; ++i)
            if (rc[i] >= (1ull << 20)) is64 = 0;   // int32 pair packed in 8B -> huge
        *flag = is64;
    }
}

// --- histogram of rows (one-time) ---
__global__ void hist_kernel(const void* __restrict__ rcv,
                            const int* __restrict__ flag,
                            unsigned int* __restrict__ cnt, int ne) {
    int e = blockIdx.x * BLK + threadIdx.x;
    if (e >= ne) return;
    unsigned int row = *flag ? (unsigned int)((const unsigned long long*)rcv)[e]
                             : ((const unsigned int*)rcv)[e];
    atomicAdd(&cnt[row], 1u);
}

// --- scan step 1: per-block exclusive scan of cnt, block totals to part[] ---
__global__ void scan1_kernel(const unsigned int* __restrict__ cnt,
                             unsigned int* __restrict__ exc,
                             unsigned int* __restrict__ part, int nv) {
    __shared__ unsigned int s[BLK];
    int t = threadIdx.x;
    int i = blockIdx.x * BLK + t;
    unsigned int v = (i < nv) ? cnt[i] : 0u;
    s[t] = v;
    __syncthreads();
    for (int off = 1; off < BLK; off <<= 1) {
        unsigned int u = (t >= off) ? s[t - off] : 0u;
        __syncthreads();
        s[t] += u;
        __syncthreads();
    }
    if (i < nv) exc[i] = s[t] - v;            // exclusive within block
    if (t == BLK - 1) part[blockIdx.x] = s[t]; // block total
}

// --- scan step 2: single-block exclusive scan of part[] (serial chunks) ---
__global__ void scan2_kernel(unsigned int* __restrict__ part, int np) {
    __shared__ unsigned int s[BLK];
    __shared__ unsigned int carry_s;
    int t = threadIdx.x;
    if (t == 0) carry_s = 0u;
    __syncthreads();
    for (int base = 0; base < np; base += BLK) {
        int i = base + t;
        unsigned int v = (i < np) ? part[i] : 0u;
        s[t] = v;
        __syncthreads();
        for (int off = 1; off < BLK; off <<= 1) {
            unsigned int u = (t >= off) ? s[t - off] : 0u;
            __syncthreads();
            s[t] += u;
            __syncthreads();
        }
        unsigned int carry = carry_s;
        if (i < np) part[i] = s[t] - v + carry;   // exclusive global
        __syncthreads();
        if (t == BLK - 1) carry_s = carry + s[t];
        __syncthreads();
    }
}

// --- scan step 3: row_ptr = exc + part[b]; init cursor; set row_ptr[nv] ---
__global__ void scan3_kernel(const unsigned int* __restrict__ exc,
                             const unsigned int* __restrict__ part,
                             unsigned int* __restrict__ row_ptr,
                             unsigned int* __restrict__ cursor, int nv, int ne) {
    int i = blockIdx.x * BLK + threadIdx.x;
    if (i >= nv) return;
    unsigned int start = exc[i] + part[blockIdx.x];
    row_ptr[i] = start;
    cursor[i]  = start;
    if (i == 0) row_ptr[nv] = (unsigned int)ne;
}

// --- scatter edges into CSR slots (one-time): edges[pos] = col | f32(a)<<32 ---
__global__ void scatter_kernel(const void* __restrict__ rcv,
                               const float2* __restrict__ eattr,
                               const int* __restrict__ flag,
                               unsigned int* __restrict__ cursor,
                               unsigned long long* __restrict__ edges, int ne) {
    int e = blockIdx.x * BLK + threadIdx.x;
    if (e >= ne) return;
    unsigned int row, col;
    if (*flag) {
        const unsigned long long* rc = (const unsigned long long*)rcv;
        row = (unsigned int)rc[e];
        col = (unsigned int)rc[(size_t)ne + e];
    } else {
        const unsigned int* rc = (const unsigned int*)rcv;
        row = rc[e];
        col = rc[(size_t)ne + e];
    }
    float a = eattr[e].x;
    unsigned int pos = atomicAdd(&cursor[row], 1u);
    edges[pos] = (unsigned long long)col |
                 ((unsigned long long)__float_as_uint(a) << 32);
}

// --- vertex preprocessing: wbA = w*b/A, wA = w/A, x0 ---
__global__ void vprep_kernel(const float* __restrict__ vattr,
                             const float* __restrict__ g,
                             float2* __restrict__ vp,
                             float* __restrict__ x0, int nv) {
    int i = blockIdx.x * BLK + threadIdx.x;
    if (i >= nv) return;
    float A = vattr[3 * i + 0];
    float b = vattr[3 * i + 1];
    float x = vattr[3 * i + 2];
    float w = g[0];
    vp[i] = make_float2(w * b / A, w / A);
    x0[i] = x;
}

// --- fused Jacobi iteration: x_out = x_in + wbA - wA * sum_j a_j * x_in[col_j] ---
__global__ void iter_kernel(const unsigned int* __restrict__ row_ptr,
                            const unsigned long long* __restrict__ edges,
                            const float2* __restrict__ vp,
                            const float* __restrict__ xin,
                            float* __restrict__ xout, int nv) {
    int i = blockIdx.x * BLK + threadIdx.x;
    if (i >= nv) return;
    unsigned int s = row_ptr[i];
    unsigned int e = row_ptr[i + 1];
    float acc = 0.0f;
    for (unsigned int j = s; j < e; ++j) {
        unsigned long long u = edges[j];
        float a = __uint_as_float((unsigned int)(u >> 32));
        acc = fmaf(a, xin[(unsigned int)u], acc);
    }
    float2 q = vp[i];
    xout[i] = xin[i] + q.x - q.y * acc;
}

extern "C" void kernel_launch(void* const* d_in, const int* in_sizes, int n_in,
                              void* d_out, int out_size, void* d_ws, size_t ws_size,
                              hipStream_t stream) {
    const float* vattr = (const float*)d_in[1];
    const void*  eij   = (const void*)d_in[2];
    const float* eattr = (const float*)d_in[3];
    const float* g     = (const float*)d_in[4];
    const int nv = in_sizes[1] / 3;   // 1,000,000
    const int ne = in_sizes[3] / 2;   // 16,000,000
    const int n_iters = 10;

    // workspace layout
    char* ws = (char*)d_ws;
    size_t off = 0;
    auto alloc = [&](size_t bytes) -> void* {
        void* p = ws + off;
        off = (off + bytes + 255) & ~(size_t)255;
        return p;
    };
    unsigned long long* edges  = (unsigned long long*)alloc((size_t)ne * 8); // 128MB
    unsigned int* cnt     = (unsigned int*)alloc((size_t)nv * 4);
    unsigned int* exc     = (unsigned int*)alloc((size_t)nv * 4);
    unsigned int* row_ptr = (unsigned int*)alloc((size_t)(nv + 1) * 4);
    unsigned int* cursor  = (unsigned int*)alloc((size_t)nv * 4);
    unsigned int* part    = (unsigned int*)alloc((size_t)((nv + BLK - 1) / BLK) * 4);
    float2* vp  = (float2*)alloc((size_t)nv * 8);
    float*  xa  = (float*) alloc((size_t)nv * 4);
    float*  xb  = (float*) alloc((size_t)nv * 4);
    int*    flag = (int*)  alloc(256);

    const int eblocks = (ne + BLK - 1) / BLK;
    const int vblocks = (nv + BLK - 1) / BLK;
    const int np      = vblocks;   // number of scan partials

    detect_kernel<<<1, 64, 0, stream>>>((const unsigned long long*)eij, flag);
    hipMemsetAsync(cnt, 0, (size_t)nv * 4, stream);
    hist_kernel<<<eblocks, BLK, 0, stream>>>(eij, flag, cnt, ne);
    scan1_kernel<<<vblocks, BLK, 0, stream>>>(cnt, exc, part, nv);
    scan2_kernel<<<1, BLK, 0, stream>>>(part, np);
    scan3_kernel<<<vblocks, BLK, 0, stream>>>(exc, part, row_ptr, cursor, nv, ne);
    scatter_kernel<<<eblocks, BLK, 0, stream>>>(eij, (const float2*)eattr, flag,
                                                cursor, edges, ne);
    vprep_kernel<<<vblocks, BLK, 0, stream>>>(vattr, g, vp, xa, nv);

    float* xin  = xa;
    float* xout = xb;
    for (int it = 0; it < n_iters; ++it) {
        float* dst = (it == n_iters - 1) ? (float*)d_out : xout;
        iter_kernel<<<vblocks, BLK, 0, stream>>>(row_ptr, edges, vp, xin, dst, nv);
        float* t = xin; xin = dst; xout = t;
    }
}

// Round 3
// 1953.117 us; speedup vs baseline: 4.0256x; 2.7571x over previous
//
#include <hip/hip_runtime.h>
#include <hip/hip_fp16.h>

static constexpr int BLK = 256;
static constexpr int B1  = 512;    // pass-1 partition blocks

// --- detect whether edgeij_pair is int64 (expected) or int32 (JAX x64 off) ---
__global__ void detect_kernel(const unsigned long long* __restrict__ rc,
                              int* __restrict__ flag) {
    if (blockIdx.x == 0 && threadIdx.x == 0) {
        int is64 = 1;
        for (int i = 0; i < 8; ++i)
            if (rc[i] >= (1ull << 20)) is64 = 0;
        *flag = is64;
    }
}

// --- pass 1a: per-block LDS histogram of row>>10 -> hist[bin*B1 + blk] ---
__global__ void hist1_kernel(const void* __restrict__ rcv,
                             const int* __restrict__ flag,
                             unsigned int* __restrict__ hist, int ne, int nb) {
    __shared__ unsigned int lh[1024];
    const int b = blockIdx.x;
    const int chunk = (ne + B1 - 1) / B1;
    const int s = b * chunk, e = min(ne, s + chunk);
    for (int i = threadIdx.x; i < 1024; i += BLK) lh[i] = 0u;
    __syncthreads();
    const int is64 = *flag;
    const unsigned long long* r64 = (const unsigned long long*)rcv;
    const unsigned int*       r32 = (const unsigned int*)rcv;
    for (int i = s + threadIdx.x; i < e; i += BLK) {
        unsigned int row = is64 ? (unsigned int)r64[i] : r32[i];
        atomicAdd(&lh[row >> 10], 1u);
    }
    __syncthreads();
    for (int i = threadIdx.x; i < nb; i += BLK)
        hist[(size_t)i * B1 + b] = lh[i];
}

// --- generic scan: per-block exclusive scan (in-place capable), totals to part ---
__global__ void scan1_kernel(unsigned int* __restrict__ data,
                             unsigned int* __restrict__ part, int n) {
    __shared__ unsigned int s[BLK];
    int t = threadIdx.x;
    int i = blockIdx.x * BLK + t;
    unsigned int v = (i < n) ? data[i] : 0u;
    s[t] = v;
    __syncthreads();
    for (int off = 1; off < BLK; off <<= 1) {
        unsigned int u = (t >= off) ? s[t - off] : 0u;
        __syncthreads();
        s[t] += u;
        __syncthreads();
    }
    if (i < n) data[i] = s[t] - v;
    if (t == BLK - 1) part[blockIdx.x] = s[t];
}

__global__ void scan2_kernel(unsigned int* __restrict__ part, int np) {
    __shared__ unsigned int s[BLK];
    __shared__ unsigned int carry_s;
    int t = threadIdx.x;
    if (t == 0) carry_s = 0u;
    __syncthreads();
    for (int base = 0; base < np; base += BLK) {
        int i = base + t;
        unsigned int v = (i < np) ? part[i] : 0u;
        s[t] = v;
        __syncthreads();
        for (int off = 1; off < BLK; off <<= 1) {
            unsigned int u = (t >= off) ? s[t - off] : 0u;
            __syncthreads();
            s[t] += u;
            __syncthreads();
        }
        unsigned int carry = carry_s;
        if (i < np) part[i] = s[t] - v + carry;
        __syncthreads();
        if (t == BLK - 1) carry_s = carry + s[t];
        __syncthreads();
    }
}

__global__ void scan3_kernel(unsigned int* __restrict__ data,
                             const unsigned int* __restrict__ part, int n) {
    int i = blockIdx.x * BLK + threadIdx.x;
    if (i < n) data[i] += part[blockIdx.x];
}

// --- pass 1b: scatter edges into bucket runs; pack (row:20|col:20|a:f16) ---
__global__ void scatter1_kernel(const void* __restrict__ rcv,
                                const float2* __restrict__ eattr,
                                const int* __restrict__ flag,
                                const unsigned int* __restrict__ base,
                                unsigned long long* __restrict__ tmp,
                                int ne, int nb) {
    __shared__ unsigned int cur[1024];
    const int b = blockIdx.x;
    const int chunk = (ne + B1 - 1) / B1;
    const int s = b * chunk, e = min(ne, s + chunk);
    for (int i = threadIdx.x; i < nb; i += BLK)
        cur[i] = base[(size_t)i * B1 + b];
    __syncthreads();
    const int is64 = *flag;
    const unsigned long long* r64 = (const unsigned long long*)rcv;
    const unsigned int*       r32 = (const unsigned int*)rcv;
    for (int i = s + threadIdx.x; i < e; i += BLK) {
        unsigned long long row, col;
        if (is64) { row = r64[i]; col = r64[(size_t)ne + i]; }
        else      { row = r32[i]; col = r32[(size_t)ne + i]; }
        float a = eattr[i].x;
        unsigned short h = __half_as_ushort(__float2half(a));
        unsigned long long q = (row << 44) | (col << 24) | (unsigned long long)h;
        unsigned int pos = atomicAdd(&cur[(unsigned int)(row >> 10)], 1u);
        tmp[pos] = q;
    }
}

// --- pass 2: per-bucket full sort by row in LDS; emit CSR edges + row_ptr ---
__global__ void bucket_sort_kernel(const unsigned long long* __restrict__ tmp,
                                   const unsigned int* __restrict__ base,
                                   unsigned long long* __restrict__ edges,
                                   unsigned int* __restrict__ row_ptr,
                                   int ne, int nv, int nb) {
    __shared__ unsigned int hist[1024];
    __shared__ unsigned int cur[1024];
    __shared__ unsigned int ss[BLK];
    const int b = blockIdx.x;
    const int t = threadIdx.x;
    const unsigned int start = base[(size_t)b * B1];
    const unsigned int end = (b == nb - 1) ? (unsigned int)ne
                                           : base[(size_t)(b + 1) * B1];
    for (int i = t; i < 1024; i += BLK) hist[i] = 0u;
    __syncthreads();
    for (unsigned int j = start + t; j < end; j += BLK) {
        unsigned int r = (unsigned int)(tmp[j] >> 44);
        atomicAdd(&hist[r & 1023u], 1u);
    }
    __syncthreads();
    // exclusive scan of 1024 bins with 256 threads (4 bins each)
    unsigned int a0 = hist[4*t], a1 = hist[4*t+1], a2 = hist[4*t+2], a3 = hist[4*t+3];
    unsigned int tsum = a0 + a1 + a2 + a3;
    ss[t] = tsum;
    __syncthreads();
    for (int off = 1; off < BLK; off <<= 1) {
        unsigned int u = (t >= off) ? ss[t - off] : 0u;
        __syncthreads();
        ss[t] += u;
        __syncthreads();
    }
    unsigned int texc = ss[t] - tsum;
    cur[4*t]   = texc;
    cur[4*t+1] = texc + a0;
    cur[4*t+2] = texc + a0 + a1;
    cur[4*t+3] = texc + a0 + a1 + a2;
    __syncthreads();
    // row_ptr for this bucket's rows
    const int r0 = b << 10;
    for (int i = t; i < 1024; i += BLK) {
        int r = r0 + i;
        if (r < nv) row_ptr[r] = start + cur[i];
    }
    if (b == nb - 1 && t == 0) row_ptr[nv] = (unsigned int)ne;
    __syncthreads();
    // scatter within bucket (LDS cursors; bucket output window is ~128KB)
    for (unsigned int j = start + t; j < end; j += BLK) {
        unsigned long long q = tmp[j];
        unsigned int r = (unsigned int)(q >> 44) & 1023u;
        unsigned int pos = atomicAdd(&cur[r], 1u);
        edges[start + pos] = q;
    }
}

// --- vertex preprocessing: wbA = w*b/A, wA = w/A, x0 ---
__global__ void vprep_kernel(const float* __restrict__ vattr,
                             const float* __restrict__ g,
                             float2* __restrict__ vp,
                             float* __restrict__ x0, int nv) {
    int i = blockIdx.x * BLK + threadIdx.x;
    if (i >= nv) return;
    float A = vattr[3 * i + 0];
    float b = vattr[3 * i + 1];
    float x = vattr[3 * i + 2];
    float w = g[0];
    vp[i] = make_float2(w * b / A, w / A);
    x0[i] = x;
}

// --- iteration phase A: products[j] = a_j * x[col_j]  (8 edges/thread) ---
__global__ void prod_kernel(const unsigned long long* __restrict__ edges,
                            const float* __restrict__ xin,
                            float* __restrict__ prod, int ne) {
    int tid = blockIdx.x * BLK + threadIdx.x;
    size_t base = (size_t)tid * 8;
    if (base + 8 > (size_t)ne) {
        for (size_t j = base; j < (size_t)ne; ++j) {
            unsigned long long q = edges[j];
            unsigned int col = (unsigned int)(q >> 24) & 0xFFFFFu;
            float a = __half2float(__ushort_as_half((unsigned short)(q & 0xFFFFu)));
            prod[j] = a * xin[col];
        }
        return;
    }
    const ulonglong2* e2 = (const ulonglong2*)(edges + base);
    ulonglong2 p0 = e2[0], p1 = e2[1], p2 = e2[2], p3 = e2[3];
    unsigned long long qs[8] = {p0.x, p0.y, p1.x, p1.y, p2.x, p2.y, p3.x, p3.y};
    float r[8];
    #pragma unroll
    for (int k = 0; k < 8; ++k) {
        unsigned int col = (unsigned int)(qs[k] >> 24) & 0xFFFFFu;
        float a = __half2float(__ushort_as_half((unsigned short)(qs[k] & 0xFFFFu)));
        r[k] = a * xin[col];
    }
    float4* o = (float4*)(prod + base);
    o[0] = make_float4(r[0], r[1], r[2], r[3]);
    o[1] = make_float4(r[4], r[5], r[6], r[7]);
}

// --- iteration phase B: quad-per-row segmented sum + Jacobi update ---
__global__ void update_kernel(const unsigned int* __restrict__ row_ptr,
                              const float* __restrict__ prod,
                              const float2* __restrict__ vp,
                              const float* __restrict__ xin,
                              float* __restrict__ xout, int nv) {
    int tid = blockIdx.x * BLK + threadIdx.x;
    int row = tid >> 2;
    int l = tid & 3;
    if (row >= nv) return;
    unsigned int s = row_ptr[row], e = row_ptr[row + 1];
    float acc = 0.0f;
    for (unsigned int j = s + l; j < e; j += 4) acc += prod[j];
    acc += __shfl_xor(acc, 1, 4);
    acc += __shfl_xor(acc, 2, 4);
    if (l == 0) {
        float2 q = vp[row];
        xout[row] = xin[row] + q.x - q.y * acc;
    }
}

extern "C" void kernel_launch(void* const* d_in, const int* in_sizes, int n_in,
                              void* d_out, int out_size, void* d_ws, size_t ws_size,
                              hipStream_t stream) {
    const float* vattr = (const float*)d_in[1];
    const void*  eij   = (const void*)d_in[2];
    const float* eattr = (const float*)d_in[3];
    const float* g     = (const float*)d_in[4];
    const int nv = in_sizes[1] / 3;   // 1,000,000
    const int ne = in_sizes[3] / 2;   // 16,000,000
    const int n_iters = 10;
    const int nb = (nv + 1023) >> 10;         // 977 buckets
    const int nh = nb * B1;                   // hist/scan length

    // workspace layout
    char* ws = (char*)d_ws;
    size_t off = 0;
    auto alloc = [&](size_t bytes) -> void* {
        void* p = ws + off;
        off = (off + bytes + 255) & ~(size_t)255;
        return p;
    };
    unsigned long long* edges = (unsigned long long*)alloc((size_t)ne * 8); // 128MB
    unsigned long long* tmp   = (unsigned long long*)alloc((size_t)ne * 8); // 128MB
    float* prod = (float*)tmp;                 // alias: prod used only after pass 2
    unsigned int* hist    = (unsigned int*)alloc((size_t)nh * 4);   // ~2MB
    unsigned int* part    = (unsigned int*)alloc(((size_t)(nh + BLK - 1) / BLK) * 4);
    unsigned int* row_ptr = (unsigned int*)alloc((size_t)(nv + 1) * 4);
    float2* vp = (float2*)alloc((size_t)nv * 8);
    float*  xa = (float*) alloc((size_t)nv * 4);
    float*  xb = (float*) alloc((size_t)nv * 4);
    int*  flag = (int*)   alloc(256);

    const int vblocks = (nv + BLK - 1) / BLK;
    const int sblocks = (nh + BLK - 1) / BLK;     // 1954
    const int pblocks = ((ne + 7) / 8 + BLK - 1) / BLK;
    const int ublocks = (4 * nv + BLK - 1) / BLK;

    detect_kernel<<<1, 64, 0, stream>>>((const unsigned long long*)eij, flag);
    hist1_kernel<<<B1, BLK, 0, stream>>>(eij, flag, hist, ne, nb);
    scan1_kernel<<<sblocks, BLK, 0, stream>>>(hist, part, nh);
    scan2_kernel<<<1, BLK, 0, stream>>>(part, sblocks);
    scan3_kernel<<<sblocks, BLK, 0, stream>>>(hist, part, nh);
    scatter1_kernel<<<B1, BLK, 0, stream>>>(eij, (const float2*)eattr, flag,
                                            hist, tmp, ne, nb);
    bucket_sort_kernel<<<nb, BLK, 0, stream>>>(tmp, hist, edges, row_ptr,
                                               ne, nv, nb);
    vprep_kernel<<<vblocks, BLK, 0, stream>>>(vattr, g, vp, xa, nv);

    float* xin  = xa;
    float* xout = xb;
    for (int it = 0; it < n_iters; ++it) {
        prod_kernel<<<pblocks, BLK, 0, stream>>>(edges, xin, prod, ne);
        float* dst = (it == n_iters - 1) ? (float*)d_out : xout;
        update_kernel<<<ublocks, BLK, 0, stream>>>(row_ptr, prod, vp, xin, dst, nv);
        float* t = xin; xin = dst; xout = t;
    }
}

// Round 4
// 1405.663 us; speedup vs baseline: 5.5934x; 1.3895x over previous
//
#include <hip/hip_runtime.h>
#include <hip/hip_fp16.h>

static constexpr int BLK  = 256;   // generic block size
static constexpr int B1   = 256;   // partition blocks for hist/scatter
static constexpr int BLKW = 1024;  // threads for hist/scatter blocks

// --- detect whether edgeij_pair is int64 (expected) or int32 (JAX x64 off) ---
__global__ void detect_kernel(const unsigned long long* __restrict__ rc,
                              int* __restrict__ flag) {
    if (blockIdx.x == 0 && threadIdx.x == 0) {
        int is64 = 1;
        for (int i = 0; i < 8; ++i)
            if (rc[i] >= (1ull << 20)) is64 = 0;
        *flag = is64;
    }
}

// --- pass 1a: per-block LDS histogram of row>>10 -> hist[bin*B1 + blk] ---
__global__ void hist1_kernel(const void* __restrict__ rcv,
                             const int* __restrict__ flag,
                             unsigned int* __restrict__ hist, int ne, int nb) {
    __shared__ unsigned int lh[1024];
    const int b = blockIdx.x;
    const int chunk = (ne + B1 - 1) / B1;
    const int s = b * chunk, e = min(ne, s + chunk);
    for (int i = threadIdx.x; i < 1024; i += BLKW) lh[i] = 0u;
    __syncthreads();
    const int is64 = *flag;
    const unsigned long long* r64 = (const unsigned long long*)rcv;
    const unsigned int*       r32 = (const unsigned int*)rcv;
    for (int i = s + threadIdx.x; i < e; i += BLKW) {
        unsigned int row = is64 ? (unsigned int)r64[i] : r32[i];
        atomicAdd(&lh[row >> 10], 1u);
    }
    __syncthreads();
    for (int i = threadIdx.x; i < nb; i += BLKW)
        hist[(size_t)i * B1 + b] = lh[i];
}

// --- generic scan: per-block exclusive scan (in-place), totals to part ---
__global__ void scan1_kernel(unsigned int* __restrict__ data,
                             unsigned int* __restrict__ part, int n) {
    __shared__ unsigned int s[BLK];
    int t = threadIdx.x;
    int i = blockIdx.x * BLK + t;
    unsigned int v = (i < n) ? data[i] : 0u;
    s[t] = v;
    __syncthreads();
    for (int off = 1; off < BLK; off <<= 1) {
        unsigned int u = (t >= off) ? s[t - off] : 0u;
        __syncthreads();
        s[t] += u;
        __syncthreads();
    }
    if (i < n) data[i] = s[t] - v;
    if (t == BLK - 1) part[blockIdx.x] = s[t];
}

__global__ void scan2_kernel(unsigned int* __restrict__ part, int np) {
    __shared__ unsigned int s[BLK];
    __shared__ unsigned int carry_s;
    int t = threadIdx.x;
    if (t == 0) carry_s = 0u;
    __syncthreads();
    for (int base = 0; base < np; base += BLK) {
        int i = base + t;
        unsigned int v = (i < np) ? part[i] : 0u;
        s[t] = v;
        __syncthreads();
        for (int off = 1; off < BLK; off <<= 1) {
            unsigned int u = (t >= off) ? s[t - off] : 0u;
            __syncthreads();
            s[t] += u;
            __syncthreads();
        }
        unsigned int carry = carry_s;
        if (i < np) part[i] = s[t] - v + carry;
        __syncthreads();
        if (t == BLK - 1) carry_s = carry + s[t];
        __syncthreads();
    }
}

__global__ void scan3_kernel(unsigned int* __restrict__ data,
                             const unsigned int* __restrict__ part, int n) {
    int i = blockIdx.x * BLK + threadIdx.x;
    if (i < n) data[i] += part[blockIdx.x];
}

// --- pass 1b: scatter edges into bucket runs; pack (row:20|col:20|a:f16) ---
__global__ void scatter1_kernel(const void* __restrict__ rcv,
                                const float2* __restrict__ eattr,
                                const int* __restrict__ flag,
                                const unsigned int* __restrict__ base,
                                unsigned long long* __restrict__ edges,
                                int ne, int nb) {
    __shared__ unsigned int cur[1024];
    const int b = blockIdx.x;
    const int chunk = (ne + B1 - 1) / B1;
    const int s = b * chunk, e = min(ne, s + chunk);
    for (int i = threadIdx.x; i < nb; i += BLKW)
        cur[i] = base[(size_t)i * B1 + b];
    __syncthreads();
    const int is64 = *flag;
    const unsigned long long* r64 = (const unsigned long long*)rcv;
    const unsigned int*       r32 = (const unsigned int*)rcv;
    for (int i = s + threadIdx.x; i < e; i += BLKW) {
        unsigned long long row, col;
        if (is64) { row = r64[i]; col = r64[(size_t)ne + i]; }
        else      { row = r32[i]; col = r32[(size_t)ne + i]; }
        float a = eattr[i].x;
        unsigned short h = __half_as_ushort(__float2half(a));
        unsigned long long q = (row << 44) | (col << 24) | (unsigned long long)h;
        unsigned int pos = atomicAdd(&cur[(unsigned int)(row >> 10)], 1u);
        edges[pos] = q;
    }
}

// --- vertex preprocessing: wbA = w*b/A, wA = w/A, x0 ---
__global__ void vprep_kernel(const float* __restrict__ vattr,
                             const float* __restrict__ g,
                             float2* __restrict__ vp,
                             float* __restrict__ x0, int nv) {
    int i = blockIdx.x * BLK + threadIdx.x;
    if (i >= nv) return;
    float A = vattr[3 * i + 0];
    float b = vattr[3 * i + 1];
    float x = vattr[3 * i + 2];
    float w = g[0];
    vp[i] = make_float2(w * b / A, w / A);
    x0[i] = x;
}

// --- fused Jacobi iteration: block b owns rows [b*1024, b*1024+1024) ---
// streams its bucket's edges, LDS-accumulates a*x[col], then updates x.
__global__ void iter_kernel(const unsigned int* __restrict__ bbase,  // hist, stride B1
                            const unsigned long long* __restrict__ edges,
                            const float2* __restrict__ vp,
                            const float* __restrict__ xin,
                            float* __restrict__ xout,
                            int nv, int ne, int nb) {
    __shared__ float acc[1024];
    const int b = blockIdx.x;
    const int t = threadIdx.x;
    for (int i = t; i < 1024; i += BLK) acc[i] = 0.0f;
    __syncthreads();
    const unsigned int s = bbase[(size_t)b * B1];
    const unsigned int e = (b == nb - 1) ? (unsigned int)ne
                                         : bbase[(size_t)(b + 1) * B1];
    #pragma unroll 4
    for (unsigned int j = s + t; j < e; j += BLK) {
        unsigned long long q = edges[j];
        float a = __half2float(__ushort_as_half((unsigned short)(q & 0xFFFFu)));
        unsigned int col = (unsigned int)(q >> 24) & 0xFFFFFu;
        unsigned int rlo = (unsigned int)(q >> 44) & 1023u;
        atomicAdd(&acc[rlo], a * xin[col]);   // ds_add_f32, no return
    }
    __syncthreads();
    const int r0 = b << 10;
    for (int i = t; i < 1024; i += BLK) {
        int r = r0 + i;
        if (r < nv) {
            float2 qv = vp[r];
            xout[r] = xin[r] + qv.x - qv.y * acc[i];
        }
    }
}

extern "C" void kernel_launch(void* const* d_in, const int* in_sizes, int n_in,
                              void* d_out, int out_size, void* d_ws, size_t ws_size,
                              hipStream_t stream) {
    const float* vattr = (const float*)d_in[1];
    const void*  eij   = (const void*)d_in[2];
    const float* eattr = (const float*)d_in[3];
    const float* g     = (const float*)d_in[4];
    const int nv = in_sizes[1] / 3;   // 1,000,000
    const int ne = in_sizes[3] / 2;   // 16,000,000
    const int n_iters = 10;
    const int nb = (nv + 1023) >> 10;         // 977 buckets of 1024 rows
    const int nh = nb * B1;                   // hist/scan length (~250K)

    // workspace layout
    char* ws = (char*)d_ws;
    size_t off = 0;
    auto alloc = [&](size_t bytes) -> void* {
        void* p = ws + off;
        off = (off + bytes + 255) & ~(size_t)255;
        return p;
    };
    unsigned long long* edges = (unsigned long long*)alloc((size_t)ne * 8); // 128MB
    unsigned int* hist = (unsigned int*)alloc((size_t)nh * 4);              // ~1MB
    unsigned int* part = (unsigned int*)alloc(((size_t)(nh + BLK - 1) / BLK) * 4);
    float2* vp = (float2*)alloc((size_t)nv * 8);
    float*  xa = (float*) alloc((size_t)nv * 4);
    float*  xb = (float*) alloc((size_t)nv * 4);
    int*  flag = (int*)   alloc(256);

    const int vblocks = (nv + BLK - 1) / BLK;
    const int sblocks = (nh + BLK - 1) / BLK;

    detect_kernel<<<1, 64, 0, stream>>>((const unsigned long long*)eij, flag);
    hist1_kernel<<<B1, BLKW, 0, stream>>>(eij, flag, hist, ne, nb);
    scan1_kernel<<<sblocks, BLK, 0, stream>>>(hist, part, nh);
    scan2_kernel<<<1, BLK, 0, stream>>>(part, sblocks);
    scan3_kernel<<<sblocks, BLK, 0, stream>>>(hist, part, nh);
    scatter1_kernel<<<B1, BLKW, 0, stream>>>(eij, (const float2*)eattr, flag,
                                             hist, edges, ne, nb);
    vprep_kernel<<<vblocks, BLK, 0, stream>>>(vattr, g, vp, xa, nv);

    float* xin  = xa;
    float* xout = xb;
    for (int it = 0; it < n_iters; ++it) {
        float* dst = (it == n_iters - 1) ? (float*)d_out : xout;
        iter_kernel<<<nb, BLK, 0, stream>>>(hist, edges, vp, xin, dst,
                                            nv, ne, nb);
        float* t = xin; xin = dst; xout = t;
    }
}